// Round 11
// baseline (120.936 us; speedup 1.0000x reference)
//
#include <hip/hip_runtime.h>
#include <hip/hip_bf16.h>
#include <stdint.h>
#include <stddef.h>

// ClusterLayer: q = normalize_rows( 1 / (1 + ||z-c||^2) )
// N=200000 rows, D=256, KC=256 clusters. fp32 in/out; cross-term via bf16 MFMA.
// R10 = R9 + 2-tiles-per-B-read: each wave-pair owns 32 consecutive rows
// (tiles 2u, 2u+1); one ds_read_b128 feeds TWO MFMAs -> LDS pipe demand per
// row halves (it was the largest serial term: 512 reads x ~12cyc per CU-iter),
// and each LDS access carries 2x independent MFMA work (better latency hiding
// at 2 waves/SIMD). acc = 2x8 f32x4 = 64 AGPR-side regs (R1-proven shape);
// ring 2-deep per tile (per-kk body is 2x longer, so cover == R9's 4-deep).

#define NT 512
#define GRID 256
#define UNITS (GRID * 4)   // wave-pair units per sweep = 1024 (each = 2 tiles)
#define D 256
#define KC 256

typedef __attribute__((ext_vector_type(8))) short short8;  // 8 bf16 (4 VGPRs)
typedef __attribute__((ext_vector_type(4))) float f32x4;   // MFMA accumulator

// fp32 -> bf16, round-to-nearest-even (branch-free) — prep kernels only
__device__ __forceinline__ short f2bf(float f) {
    uint32_t u = __builtin_bit_cast(uint32_t, f);
    u += 0x7FFFu + ((u >> 16) & 1u);
    return (short)(u >> 16);
}

// packed RNE f32x2 -> bf16x2 (emits v_cvt_pk_bf16_f32)
__device__ __forceinline__ unsigned int pk2(float a, float b) {
    __hip_bfloat162 h = __float22bfloat162_rn(make_float2(a, b));
    unsigned int r;
    __builtin_memcpy(&r, &h, 4);
    return r;
}

// csq[k] = ||c_k||^2 ; one wave per cluster row.
__global__ void prep_csq(const float* __restrict__ C, float* __restrict__ csq) {
    const int k = blockIdx.x;
    const int l = threadIdx.x;  // 0..63
    float4 v = *(const float4*)(C + k * D + l * 4);
    float s = v.x * v.x + v.y * v.y + v.z * v.z + v.w * v.w;
#pragma unroll
    for (int off = 32; off > 0; off >>= 1) s += __shfl_down(s, off);
    if (l == 0) csq[k] = s;
}

// Reorder C into MFMA-B fragment order, bf16 (verified R1-R9):
// Bf[((kk*16 + ct)*64 + lane)*8 + e] = bf16( C[(ct*16 + (lane&15))*D + kk*32 + (lane>>4)*8 + e] )
__global__ void prep_reorder(const float* __restrict__ C, unsigned short* __restrict__ Bf) {
    const int kk = blockIdx.x >> 4;   // 0..7
    const int ct = blockIdx.x & 15;   // 0..15
    const int lane = threadIdx.x;     // 0..63
    const int l15 = lane & 15;
    const int lg = lane >> 4;
    const float* src = C + (size_t)(ct * 16 + l15) * D + kk * 32 + lg * 8;
    float4 a0 = *(const float4*)(src);
    float4 a1 = *(const float4*)(src + 4);
    ushort4 p0, p1;
    p0.x = (unsigned short)f2bf(a0.x); p0.y = (unsigned short)f2bf(a0.y);
    p0.z = (unsigned short)f2bf(a0.z); p0.w = (unsigned short)f2bf(a0.w);
    p1.x = (unsigned short)f2bf(a1.x); p1.y = (unsigned short)f2bf(a1.y);
    p1.z = (unsigned short)f2bf(a1.z); p1.w = (unsigned short)f2bf(a1.w);
    unsigned short* dst = Bf + ((size_t)(kk * 16 + ct) * 64 + lane) * 8;
    *(ushort4*)(dst) = p0;
    *(ushort4*)(dst + 4) = p1;
}

__global__ void __launch_bounds__(NT)
main_kernel(const float* __restrict__ z,
            const uint4* __restrict__ Bf,
            const float* __restrict__ csq,
            float* __restrict__ out, int ntiles) {
    __shared__ uint4 ldsB[8192];                        // 128KB fragment-ordered bf16 B
    __shared__ __align__(16) float ldsRS[2][8][2][16];  // [parity][wave][tile][row]

    const int tid  = threadIdx.x;
    const int lane = tid & 63;
    const int wave = tid >> 6;           // 0..7
    const int l15  = lane & 15;
    const int lg   = lane >> 4;          // 0..3
    const int half = wave & 1;           // which 128-col half of the tiles
    const int pair = wave >> 1;          // unit index within block (0..3)

    // stage whole B once (16 x dwordx4 per thread), linear -> conflict-free
#pragma unroll
    for (int i = 0; i < 16; ++i) ldsB[tid + i * NT] = Bf[tid + i * NT];
    __syncthreads();

    // c_sq for this lane's 8 columns (col = half*128 + ct*16 + l15)
    float csqr[8];
#pragma unroll
    for (int ct = 0; ct < 8; ++ct) csqr[ct] = csq[half * 128 + ct * 16 + l15];

    const char* ldsb = (const char*)ldsB;
    const int laneoff = (lane << 4) + (half << 13);  // lane*16 + half*8 frag-blocks

    const int nunits = ntiles >> 1;                  // 6250 (ntiles even)
    // per-block iteration count (tail-balanced)
    const int niter = (nunits - blockIdx.x * 4 + UNITS - 1) / UNITS;

    int u = blockIdx.x * 4 + pair;                   // < 1024 <= nunits: initially valid

    // unit u owns rows [u*32, u*32+32): tile a = rows u*32+l15, tile b = +16
    const float* zrow_a = z + ((size_t)u * 32 + l15) * D + lg * 8;
    const float* zrow_b = zrow_a + 16 * D;
    // 2-deep rolling ring per tile: slot kk&1 holds k-step kk; refill with kk+2.
    float4 Sa0[2], Sa1[2], Sb0[2], Sb1[2];
#pragma unroll
    for (int s = 0; s < 2; ++s) {
        Sa0[s] = *(const float4*)(zrow_a + s * 32);
        Sa1[s] = *(const float4*)(zrow_a + s * 32 + 4);
        Sb0[s] = *(const float4*)(zrow_b + s * 32);
        Sb1[s] = *(const float4*)(zrow_b + s * 32 + 4);
    }

    for (int i = 0; i < niter; ++i) {
        const bool active = u < nunits;
        const int un = u + UNITS;
        const int unc = (un < nunits) ? un : (nunits - 1);
        const float* zrow_na = z + ((size_t)unc * 32 + l15) * D + lg * 8;
        const float* zrow_nb = zrow_na + 16 * D;

        f32x4 accA[8], accB[8];
        const f32x4 zero4 = {0.f, 0.f, 0.f, 0.f};
#pragma unroll
        for (int ct = 0; ct < 8; ++ct) { accA[ct] = zero4; accB[ct] = zero4; }
        float zsq_a = 0.f, zsq_b = 0.f;

#pragma unroll
        for (int kk = 0; kk < 8; ++kk) {
            // consume ring slot kk&1, refill with k-step kk+2
            // (kk>=6 refills from the NEXT unit's k-steps 0,1)
            float4 ca0 = Sa0[kk & 1], ca1 = Sa1[kk & 1];
            float4 cb0 = Sb0[kk & 1], cb1 = Sb1[kk & 1];
            const float* pfa = (kk < 6) ? (zrow_a + (kk + 2) * 32) : (zrow_na + (kk - 6) * 32);
            const float* pfb = (kk < 6) ? (zrow_b + (kk + 2) * 32) : (zrow_nb + (kk - 6) * 32);
            Sa0[kk & 1] = *(const float4*)(pfa);
            Sa1[kk & 1] = *(const float4*)(pfa + 4);
            Sb0[kk & 1] = *(const float4*)(pfb);
            Sb1[kk & 1] = *(const float4*)(pfb + 4);

            zsq_a += ca0.x * ca0.x + ca0.y * ca0.y + ca0.z * ca0.z + ca0.w * ca0.w +
                     ca1.x * ca1.x + ca1.y * ca1.y + ca1.z * ca1.z + ca1.w * ca1.w;
            zsq_b += cb0.x * cb0.x + cb0.y * cb0.y + cb0.z * cb0.z + cb0.w * cb0.w +
                     cb1.x * cb1.x + cb1.y * cb1.y + cb1.z * cb1.z + cb1.w * cb1.w;
            // packed RNE conversion: v_cvt_pk_bf16_f32
            uint4 ua, ub;
            ua.x = pk2(ca0.x, ca0.y); ua.y = pk2(ca0.z, ca0.w);
            ua.z = pk2(ca1.x, ca1.y); ua.w = pk2(ca1.z, ca1.w);
            ub.x = pk2(cb0.x, cb0.y); ub.y = pk2(cb0.z, cb0.w);
            ub.z = pk2(cb1.x, cb1.y); ub.w = pk2(cb1.z, cb1.w);
            short8 afa, afb;
            __builtin_memcpy(&afa, &ua, 16);
            __builtin_memcpy(&afb, &ub, 16);
#pragma unroll
            for (int ct = 0; ct < 8; ++ct) {
                // one linear conflict-free ds_read feeds BOTH tiles' MFMAs
                short8 bf = *(const short8*)(ldsb + laneoff + ((kk * 16 + ct) << 10));
                accA[ct] = __builtin_amdgcn_mfma_f32_16x16x32_bf16(afa, bf, accA[ct], 0, 0, 0);
                accB[ct] = __builtin_amdgcn_mfma_f32_16x16x32_bf16(afb, bf, accB[ct], 0, 0, 0);
            }
        }
        // ring now holds next unit's k-steps 0,1 (loads may still be in flight)

        // ||z_row||^2 per tile: lane holds partial for row l15; sum lane-groups
        float zsqj_a[4], zsqj_b[4];
        {
            float za = zsq_a;
            za += __shfl_xor(za, 16);
            za += __shfl_xor(za, 32);
            float zb = zsq_b;
            zb += __shfl_xor(zb, 16);
            zb += __shfl_xor(zb, 32);
#pragma unroll
            for (int j = 0; j < 4; ++j) {
                zsqj_a[j] = __shfl(za, lg * 4 + j);
                zsqj_b[j] = __shfl(zb, lg * 4 + j);
            }
        }

        // q = 1/(1+dist); per-lane partial row sums over this wave's 8 col-frags
        float rsA[4] = {0.f, 0.f, 0.f, 0.f}, rsB[4] = {0.f, 0.f, 0.f, 0.f};
#pragma unroll
        for (int ct = 0; ct < 8; ++ct) {
#pragma unroll
            for (int j = 0; j < 4; ++j) {
                float da = zsqj_a[j] + csqr[ct] - 2.0f * accA[ct][j];
                float db = zsqj_b[j] + csqr[ct] - 2.0f * accB[ct][j];
                da = fmaxf(da, 0.f);
                db = fmaxf(db, 0.f);
                float qa = 1.0f / (1.0f + da);
                float qb = 1.0f / (1.0f + db);
                accA[ct][j] = qa; rsA[j] += qa;
                accB[ct][j] = qb; rsB[j] += qb;
            }
        }
        // reduce over the 16-lane column group -> this wave's 128-col row sums
#pragma unroll
        for (int j = 0; j < 4; ++j) {
            float sa = rsA[j], sb = rsB[j];
            sa += __shfl_xor(sa, 1); sb += __shfl_xor(sb, 1);
            sa += __shfl_xor(sa, 2); sb += __shfl_xor(sb, 2);
            sa += __shfl_xor(sa, 4); sb += __shfl_xor(sb, 4);
            sa += __shfl_xor(sa, 8); sb += __shfl_xor(sb, 8);
            rsA[j] = sa; rsB[j] = sb;
        }
        // exchange with partner wave (other 128 cols), parity double-buffered
        if (l15 == 0) {
            float4 wa = {rsA[0], rsA[1], rsA[2], rsA[3]};
            float4 wb = {rsB[0], rsB[1], rsB[2], rsB[3]};
            *(float4*)&ldsRS[i & 1][wave][0][lg * 4] = wa;
            *(float4*)&ldsRS[i & 1][wave][1][lg * 4] = wb;
        }
        asm volatile("s_waitcnt lgkmcnt(0)" ::: "memory");
        __builtin_amdgcn_s_barrier();          // raw: vmcnt NOT drained
        __builtin_amdgcn_sched_barrier(0);
        float4 pa = *(const float4*)&ldsRS[i & 1][wave ^ 1][0][lg * 4];
        float4 pb = *(const float4*)&ldsRS[i & 1][wave ^ 1][1][lg * 4];
        float invA[4], invB[4];
        invA[0] = 1.0f / (rsA[0] + pa.x); invB[0] = 1.0f / (rsB[0] + pb.x);
        invA[1] = 1.0f / (rsA[1] + pa.y); invB[1] = 1.0f / (rsB[1] + pb.y);
        invA[2] = 1.0f / (rsA[2] + pa.z); invB[2] = 1.0f / (rsB[2] + pb.z);
        invA[3] = 1.0f / (rsA[3] + pa.w); invB[3] = 1.0f / (rsB[3] + pb.w);

        if (active) {
#pragma unroll
            for (int j = 0; j < 4; ++j) {
                float* orow = out + ((size_t)u * 32 + lg * 4 + j) * KC + half * 128 + l15;
#pragma unroll
                for (int ct = 0; ct < 8; ++ct) {
                    orow[ct * 16] = accA[ct][j] * invA[j];
                    orow[16 * KC + ct * 16] = accB[ct][j] * invB[j];
                }
            }
        }
        u = un;
        zrow_a = zrow_na;
        zrow_b = zrow_nb;
    }
}

extern "C" void kernel_launch(void* const* d_in, const int* in_sizes, int n_in,
                              void* d_out, int out_size, void* d_ws, size_t ws_size,
                              hipStream_t stream) {
    const float* zp = (const float*)d_in[0];
    const float* Cp = (const float*)d_in[1];
    const int N = in_sizes[0] / D;  // 200000
    unsigned short* Bf = (unsigned short*)d_ws;                          // 128KB bf16 frag-ordered
    float* csq = (float*)((char*)d_ws + (size_t)KC * D * sizeof(unsigned short));  // 1KB

    prep_csq<<<KC, 64, 0, stream>>>(Cp, csq);
    prep_reorder<<<128, 64, 0, stream>>>(Cp, Bf);

    const int ntiles = (N + 15) / 16;  // 12500
    main_kernel<<<GRID, NT, 0, stream>>>(zp, (const uint4*)Bf, csq, (float*)d_out, ntiles);
}